// Round 2
// baseline (6954.373 us; speedup 1.0000x reference)
//
#include <hip/hip_runtime.h>

typedef _Float16 half2_t __attribute__((ext_vector_type(2)));
typedef unsigned int uint4_t __attribute__((ext_vector_type(4)));
typedef float float4_t __attribute__((ext_vector_type(4)));

#define T_STEPS 2048
#define NREG    96      // f16 pairs of W_hh row kept in VGPRs (192 elements)
#define NTAIL   32      // f16 pair-dwords of W_hh row kept in LDS (64 elements)
#define TSTRIDE 33      // tail row stride in dwords (132B: bank = tid+2s mod 32, 2-way = free)

// LDS map (bytes)
#define TAIL_OFF 0                        // 1024 rows * 132 B          = 135168
#define X_OFF    135168                   // 2048 f32 x[b,:]            = 8192
#define G_OFF    (X_OFF + 8192)           // 1024 f32 gate activations  = 4096
#define R_OFF    (G_OFF + 4096)           // 256 f32 fc partials        = 1024
#define HH_OFF   (R_OFF + 1024)           // 256 f16 h hi               = 512
#define HL_OFF   (HH_OFF + 512)           // 256 f16 h lo (residual)    = 512
#define SMEM_BYTES (HL_OFF + 512)         // 149504

__device__ __forceinline__ float fdot2(half2_t a, half2_t b, float c) {
#if __has_builtin(__builtin_amdgcn_fdot2)
    return __builtin_amdgcn_fdot2(a, b, c, false);
#else
    return c + (float)a[0] * (float)b[0] + (float)a[1] * (float)b[1];
#endif
}

__device__ __forceinline__ half2_t bchalf2(unsigned u) {
    return __builtin_bit_cast(half2_t, u);
}

__device__ __forceinline__ float rcp_fast(float x) {
#if __has_builtin(__builtin_amdgcn_rcpf)
    return __builtin_amdgcn_rcpf(x);
#else
    return 1.0f / x;
#endif
}

// sigmoid/tanh via fast exp + rcp; inf-safe at both ends.
__device__ __forceinline__ float sigmoid_f(float x) {
    return rcp_fast(1.0f + __expf(-x));
}
__device__ __forceinline__ float tanh_f(float x) {
    return 1.0f - 2.0f * rcp_fast(__expf(2.0f * x) + 1.0f);
}

__global__ __launch_bounds__(1024) void lstm_fused(
    const float* __restrict__ x,      // [128, 2048]
    const float* __restrict__ W_ih,   // [1024, 1]
    const float* __restrict__ W_hh,   // [1024, 256]
    const float* __restrict__ b_ih,   // [1024]
    const float* __restrict__ b_hh,   // [1024]
    const float* __restrict__ W_fc,   // [1, 256]
    const float* __restrict__ b_fc,   // [1]
    float* __restrict__ out)          // [128, 2048]
{
    extern __shared__ __align__(16) char smem[];
    unsigned*       tailp  = (unsigned*)(smem + TAIL_OFF);
    float*          x_lds  = (float*)(smem + X_OFF);
    float*          g_lds  = (float*)(smem + G_OFF);
    float*          r_lds  = (float*)(smem + R_OFF);
    unsigned short* hh_lds = (unsigned short*)(smem + HH_OFF);
    unsigned short* hl_lds = (unsigned short*)(smem + HL_OFF);

    const int tid  = threadIdx.x;
    const int b    = blockIdx.x;
    const int lane = tid & 63;
    const int wave = tid >> 6;

    // ---- preload x[b, :] (8 KiB, broadcast-read every step)
    for (int i = tid; i < T_STEPS; i += 1024)
        x_lds[i] = x[b * T_STEPS + i];

    // ---- load W_hh row `tid`, f32->f16 pairs: 96 pairs to VGPRs, 32 pair-dwords to LDS
    half2_t wreg[NREG];
    {
        const float4_t* wrow = (const float4_t*)(W_hh + tid * 256);
        #pragma unroll
        for (int q = 0; q < 64; ++q) {
            float4_t v = wrow[q];
            half2_t p0 = { (_Float16)v.x, (_Float16)v.y };
            half2_t p1 = { (_Float16)v.z, (_Float16)v.w };
            const int pi = 2 * q;
            if (pi < NREG)     wreg[pi] = p0;
            else               tailp[tid * TSTRIDE + (pi - NREG)]     = __builtin_bit_cast(unsigned, p0);
            if (pi + 1 < NREG) wreg[pi + 1] = p1;
            else               tailp[tid * TSTRIDE + (pi + 1 - NREG)] = __builtin_bit_cast(unsigned, p1);
        }
    }

    const float w_ih_g = W_ih[tid];
    const float bsum   = b_ih[tid] + b_hh[tid];
    const float wfc    = (tid < 256) ? W_fc[tid] : 0.0f;
    const float bfc    = b_fc[0];
    const int   gtype  = tid >> 8;     // 0=i 1=f 2=g 3=o (wave-uniform)

    float c = 0.0f;
    if (tid < 256) { hh_lds[tid] = 0; hl_lds[tid] = 0; }
    __syncthreads();

    const uint4_t* hhq = (const uint4_t*)hh_lds;       // 32 chunks of 4 pair-dwords
    const uint4_t* hlq = (const uint4_t*)hl_lds;
    const unsigned* trow = tailp + tid * TSTRIDE;

    for (int t = 0; t < T_STEPS; ++t) {
        // ---- phase A: preact = bias + x*W_ih + <W, hh> + <W, hl>   (h exact via split)
        float ah0 = fmaf(w_ih_g, x_lds[t], bsum);
        float ah1 = 0.0f, al0 = 0.0f, al1 = 0.0f;
        #pragma unroll
        for (int cc = 0; cc < 24; ++cc) {              // 96 VGPR-resident pairs
            uint4_t h4 = hhq[cc];
            uint4_t l4 = hlq[cc];
            ah0 = fdot2(wreg[4*cc+0], bchalf2(h4.x), ah0);
            ah1 = fdot2(wreg[4*cc+1], bchalf2(h4.y), ah1);
            ah0 = fdot2(wreg[4*cc+2], bchalf2(h4.z), ah0);
            ah1 = fdot2(wreg[4*cc+3], bchalf2(h4.w), ah1);
            al0 = fdot2(wreg[4*cc+0], bchalf2(l4.x), al0);
            al1 = fdot2(wreg[4*cc+1], bchalf2(l4.y), al1);
            al0 = fdot2(wreg[4*cc+2], bchalf2(l4.z), al0);
            al1 = fdot2(wreg[4*cc+3], bchalf2(l4.w), al1);
        }
        #pragma unroll
        for (int cc = 24; cc < 32; ++cc) {             // 32 LDS-tail pair-dwords
            uint4_t h4 = hhq[cc];
            uint4_t l4 = hlq[cc];
            const int s = 4 * (cc - 24);
            unsigned w0 = trow[s + 0], w1 = trow[s + 1];
            unsigned w2 = trow[s + 2], w3 = trow[s + 3];
            ah0 = fdot2(bchalf2(w0), bchalf2(h4.x), ah0);
            ah1 = fdot2(bchalf2(w1), bchalf2(h4.y), ah1);
            ah0 = fdot2(bchalf2(w2), bchalf2(h4.z), ah0);
            ah1 = fdot2(bchalf2(w3), bchalf2(h4.w), ah1);
            al0 = fdot2(bchalf2(w0), bchalf2(l4.x), al0);
            al1 = fdot2(bchalf2(w1), bchalf2(l4.y), al1);
            al0 = fdot2(bchalf2(w2), bchalf2(l4.z), al0);
            al1 = fdot2(bchalf2(w3), bchalf2(l4.w), al1);
        }
        const float preact = (ah0 + ah1) + (al0 + al1);
        g_lds[tid] = (gtype == 2) ? tanh_f(preact) : sigmoid_f(preact);
        __syncthreads();                                // B1: gates ready

        // ---- phase B: c/h update (threads 0..255 own hidden unit j=tid)
        if (tid < 256) {
            const float gi = g_lds[tid];
            const float gf = g_lds[256 + tid];
            const float gg = g_lds[512 + tid];
            const float go = g_lds[768 + tid];
            c = fmaf(gf, c, gi * gg);
            const float h = go * tanh_f(c);
            const _Float16 hh = (_Float16)h;
            const _Float16 hl = (_Float16)(h - (float)hh);
            hh_lds[tid] = __builtin_bit_cast(unsigned short, hh);
            hl_lds[tid] = __builtin_bit_cast(unsigned short, hl);
            r_lds[tid]  = h * wfc;
        }
        __syncthreads();                                // B2: h + fc partials ready

        // ---- phase C: fused FC for step t, rotating wave (off critical path)
        if (wave == (t & 15)) {
            float s = (r_lds[lane] + r_lds[64 + lane]) +
                      (r_lds[128 + lane] + r_lds[192 + lane]);
            #pragma unroll
            for (int k = 32; k >= 1; k >>= 1) s += __shfl_xor(s, k);
            if (lane == 0) out[b * T_STEPS + t] = sigmoid_f(s + bfc);
        }
    }
}

extern "C" void kernel_launch(void* const* d_in, const int* in_sizes, int n_in,
                              void* d_out, int out_size, void* d_ws, size_t ws_size,
                              hipStream_t stream) {
    (void)in_sizes; (void)n_in; (void)d_ws; (void)ws_size; (void)out_size;
    const float* x    = (const float*)d_in[0];
    const float* W_ih = (const float*)d_in[1];
    const float* W_hh = (const float*)d_in[2];
    const float* b_ih = (const float*)d_in[3];
    const float* b_hh = (const float*)d_in[4];
    const float* W_fc = (const float*)d_in[5];
    const float* b_fc = (const float*)d_in[6];

    hipFuncSetAttribute(reinterpret_cast<const void*>(lstm_fused),
                        hipFuncAttributeMaxDynamicSharedMemorySize, SMEM_BYTES);
    lstm_fused<<<dim3(128), dim3(1024), SMEM_BYTES, stream>>>(
        x, W_ih, W_hh, b_ih, b_hh, W_fc, b_fc, (float*)d_out);
}